// Round 3
// baseline (10782.868 us; speedup 1.0000x reference)
//
#include <hip/hip_runtime.h>
#include <hip/hip_fp16.h>

// Problem constants
#define Bn  256
#define Tn  512
#define En  256
#define Hn  512
#define G4n 2048   // 4*H
#define KKn 768    // E + H
#define FHn 512

typedef _Float16 f16;
typedef _Float16 f16x8 __attribute__((ext_vector_type(8)));
typedef _Float16 f16x4 __attribute__((ext_vector_type(4)));
typedef float    f32x4 __attribute__((ext_vector_type(4)));

#define LDK 776   // padded row length for LDS tiles (16B-aligned stride, breaks bank patterns)

__device__ __forceinline__ float frcp(float x) { return __builtin_amdgcn_rcpf(x); }
__device__ __forceinline__ float fsig(float x) { return frcp(1.f + __expf(-x)); }
__device__ __forceinline__ float ftanh(float x) {
  x = fminf(fmaxf(x, -15.f), 15.f);
  float e = __expf(2.f * x);
  return 1.f - 2.f * frcp(e + 1.f);
}

// ---------------------------------------------------------------------------
// prep: lengths[b], zero flags, zero h-buffer[0]
// ---------------------------------------------------------------------------
__global__ void prep_kernel(const int* __restrict__ seq, int* __restrict__ lengths,
                            int* __restrict__ flags, f16* __restrict__ hbuf) {
  const int b = blockIdx.x, tid = threadIdx.x;
  __shared__ int red[256];
  int cnt = 0;
  for (int t = tid; t < Tn; t += 256) cnt += (seq[b * Tn + t] != 0) ? 1 : 0;
  red[tid] = cnt;
  __syncthreads();
  for (int s = 128; s > 0; s >>= 1) { if (tid < s) red[tid] += red[tid + s]; __syncthreads(); }
  if (tid == 0) { lengths[b] = red[0]; flags[b] = 0; }
  f16* row = hbuf + (size_t)b * Hn;   // hbuf[0][b][:]
  for (int k = tid; k < Hn; k += 256) row[k] = (f16)0.f;
}

// ---------------------------------------------------------------------------
// Persistent cooperative LSTM kernel.
// Grid = 256 blocks: ig = blockIdx>>6 (batch group of 64), jg = blockIdx&63
// (owns h-cols jg*8..jg*8+8, i.e. gate cols {g*512 + jg*8 + 0..8}).
// LDS: act[64][768] f16 = [x_t ; h_t] per batch; wt[32][768] f16 (row = g*8+h).
// h exchanged via double-buffered global f16 hbuf with flag sync per step.
// Flag protocol is deadlock-free (each block publishes before polling); the
// poll additionally carries a watchdog so any failure degrades to a wrong
// answer instead of a wedged GPU.
// ---------------------------------------------------------------------------
__global__ __launch_bounds__(256)
void lstm_kernel(const int* __restrict__ seq, const float* __restrict__ emb,
                 const float* __restrict__ Wi, const float* __restrict__ Wh,
                 const float* __restrict__ bl,
                 const int* __restrict__ lengths, int* __restrict__ flags,
                 f16* __restrict__ hbuf)
{
  __shared__ f16 act[64][LDK];
  __shared__ f16 wt[32][LDK];

  const int tid   = threadIdx.x;
  const int bx    = blockIdx.x;
  const int ig    = bx >> 6;
  const int jg    = bx & 63;
  const int bbase = ig * 64;
  const int lane  = tid & 63;
  const int wv    = tid >> 6;          // wave 0..3, handles batch rows wv*16..+16

  // ---- stage weight slice once: wt[g*8+h][k], k<256 from Wi, else Wh ----
  {
    const int h = tid & 7, g = (tid >> 3) & 3, k0 = tid >> 5;  // k0 in 0..7
    const int gc = g * Hn + jg * 8 + h;
    for (int k = k0; k < KKn; k += 8) {
      float w = (k < En) ? Wi[(size_t)k * G4n + gc] : Wh[(size_t)(k - En) * G4n + gc];
      wt[g * 8 + h][k] = (f16)w;
    }
  }

  const int ca    = lane & 15;      // MFMA M/N index
  const int hcol  = ca & 7;
  const int gA    = ca >> 3;        // 0 -> gate i (or g), 1 -> gate f (or o)
  const float biasA = bl[gA * Hn + jg * 8 + hcol];         // i/f bias
  const float biasB = bl[(2 + gA) * Hn + jg * 8 + hcol];   // g/o bias

  int   lens[4], brow[4];
  float hreg[4] = {0.f, 0.f, 0.f, 0.f};
  float creg[4] = {0.f, 0.f, 0.f, 0.f};
#pragma unroll
  for (int j = 0; j < 4; ++j) {
    brow[j] = bbase + wv * 16 + ((lane >> 4) & 3) * 4 + j;   // MFMA C/D row map
    lens[j] = lengths[brow[j]];
  }
  const bool active = (lane & 8) == 0;  // lanes that own (batch, hcol) state

  // ---- initial staging: x(t=0) and h from hbuf[0] (zeros) ----
  for (int r = wv; r < 64; r += 4) {
    int tok = seq[(size_t)(bbase + r) * Tn + 0];
    const float4 v = *(const float4*)(emb + (size_t)tok * En + lane * 4);
    f16x4 o = { (f16)v.x, (f16)v.y, (f16)v.z, (f16)v.w };
    *(f16x4*)&act[r][lane * 4] = o;
  }
  for (int r = wv; r < 64; r += 4) {
    f16x8 hv = *(const f16x8*)(hbuf + (size_t)(bbase + r) * Hn + lane * 8);
    *(f16x8*)&act[r][En + lane * 8] = hv;
  }
  __syncthreads();

  const int arow = wv * 16 + ca;        // MFMA A row (batch within group)
  const int koff = (lane >> 4) * 8;     // per-lane k offset within 32-k tile
  int cur = 0;

  for (int t = 0; t < Tn; ++t) {
    f32x4 acc0 = {0.f, 0.f, 0.f, 0.f};  // gate cols 0..15  (i | f)
    f32x4 acc1 = {0.f, 0.f, 0.f, 0.f};  // gate cols 16..31 (g | o)
#pragma unroll
    for (int kt = 0; kt < KKn; kt += 32) {
      f16x8 a  = *(const f16x8*)&act[arow][kt + koff];
      f16x8 b0 = *(const f16x8*)&wt[ca][kt + koff];
      f16x8 b1 = *(const f16x8*)&wt[16 + ca][kt + koff];
      acc0 = __builtin_amdgcn_mfma_f32_16x16x32_f16(a, b0, acc0, 0, 0, 0);
      acc1 = __builtin_amdgcn_mfma_f32_16x16x32_f16(a, b1, acc1, 0, 0, 0);
    }
#pragma unroll
    for (int j = 0; j < 4; ++j) { acc0[j] += biasA; acc1[j] += biasB; }

    // exchange with partner lane (^8): partner holds f / o for the same hcol
    float p0[4], p1[4];
#pragma unroll
    for (int j = 0; j < 4; ++j) {
      p0[j] = __shfl_xor(acc0[j], 8, 64);
      p1[j] = __shfl_xor(acc1[j], 8, 64);
    }

    const int nxt = cur ^ 1;
    if (active) {
      f16* hb = hbuf + (size_t)nxt * Bn * Hn;
#pragma unroll
      for (int j = 0; j < 4; ++j) {
        float iv = fsig(acc0[j]);
        float fv = fsig(p0[j]);
        float gv = ftanh(acc1[j]);
        float ov = fsig(p1[j]);
        float cn = fv * creg[j] + iv * gv;
        float hn = ov * ftanh(cn);
        if (t < lens[j]) { creg[j] = cn; hreg[j] = hn; }
        hb[(size_t)brow[j] * Hn + jg * 8 + hcol] = (f16)hreg[j];  // always write
      }
    }
    __syncthreads();              // per-wave s_waitcnt vmcnt(0) -> all h stores in L2
    if (t == Tn - 1) break;

    if (tid == 0) {
      __builtin_amdgcn_fence(__ATOMIC_RELEASE, "agent");   // L2 writeback for this XCD
      __hip_atomic_store(&flags[bx], t + 1, __ATOMIC_RELAXED, __HIP_MEMORY_SCOPE_AGENT);
    }

    // stage x for t+1 (independent of other blocks -> overlaps their progress)
    for (int r = wv; r < 64; r += 4) {
      int tok = seq[(size_t)(bbase + r) * Tn + (t + 1)];
      const float4 v = *(const float4*)(emb + (size_t)tok * En + lane * 4);
      f16x4 o = { (f16)v.x, (f16)v.y, (f16)v.z, (f16)v.w };
      *(f16x4*)&act[r][lane * 4] = o;
    }

    // wait for the whole row group to publish h(t+1); bounded watchdog
    if (wv == 0) {
      const int* fl = flags + ig * 64;
      const int target = t + 1;
      int guard = 0;
      while (true) {
        int v = __hip_atomic_load(&fl[lane], __ATOMIC_RELAXED, __HIP_MEMORY_SCOPE_AGENT);
        if (__all(v >= target)) break;
        if (++guard > (1 << 14)) break;    // degrade to wrong answer, never wedge
        __builtin_amdgcn_s_sleep(4);
      }
    }
    __syncthreads();
    __builtin_amdgcn_fence(__ATOMIC_ACQUIRE, "agent");     // invalidate L1/L2 before h read

    // stage h(t+1)
    {
      const f16* hb = hbuf + (size_t)nxt * Bn * Hn;
      for (int r = wv; r < 64; r += 4) {
        f16x8 hv = *(const f16x8*)(hb + (size_t)(bbase + r) * Hn + lane * 8);
        *(f16x8*)&act[r][En + lane * 8] = hv;
      }
    }
    __syncthreads();
    cur = nxt;
  }
}

// ---------------------------------------------------------------------------
// FF head: hidden = tanh(h @ W1 + b1); logits = hidden @ W2 + b2; softmax.
// One block per batch. Final h lives in hbuf[0] (written at t=511).
// ---------------------------------------------------------------------------
__global__ void ff_kernel(const f16* __restrict__ hbuf0, const float* __restrict__ W1,
                          const float* __restrict__ b1, const float* __restrict__ W2,
                          const float* __restrict__ b2, float* __restrict__ out) {
  const int b = blockIdx.x, tid = threadIdx.x;
  __shared__ float hl[Hn];
  __shared__ float hid[FHn];
  __shared__ float red0[256], red1[256];
  for (int k = tid; k < Hn; k += 256) hl[k] = (float)hbuf0[(size_t)b * Hn + k];
  __syncthreads();
  for (int j = tid; j < FHn; j += 256) {
    float s = b1[j];
    for (int k = 0; k < Hn; ++k) s += hl[k] * W1[(size_t)k * FHn + j];
    hid[j] = ftanh(s);
  }
  __syncthreads();
  float p0 = 0.f, p1 = 0.f;
  for (int j = tid; j < FHn; j += 256) {
    p0 += hid[j] * W2[j * 2 + 0];
    p1 += hid[j] * W2[j * 2 + 1];
  }
  red0[tid] = p0; red1[tid] = p1;
  __syncthreads();
  for (int s = 128; s > 0; s >>= 1) {
    if (tid < s) { red0[tid] += red0[tid + s]; red1[tid] += red1[tid + s]; }
    __syncthreads();
  }
  if (tid == 0) {
    float l0 = red0[0] + b2[0], l1 = red1[0] + b2[1];
    float m = fmaxf(l0, l1);
    float e0 = __expf(l0 - m), e1 = __expf(l1 - m);
    float inv = frcp(e0 + e1);
    out[b * 2 + 0] = e0 * inv;
    out[b * 2 + 1] = e1 * inv;
  }
}

// ---------------------------------------------------------------------------
extern "C" void kernel_launch(void* const* d_in, const int* in_sizes, int n_in,
                              void* d_out, int out_size, void* d_ws, size_t ws_size,
                              hipStream_t stream) {
  const int*   seq = (const int*)d_in[0];
  const float* emb = (const float*)d_in[1];
  const float* Wi  = (const float*)d_in[2];
  const float* Wh  = (const float*)d_in[3];
  const float* bl  = (const float*)d_in[4];
  const float* W1  = (const float*)d_in[5];
  const float* b1  = (const float*)d_in[6];
  const float* W2  = (const float*)d_in[7];
  const float* b2  = (const float*)d_in[8];
  (void)in_sizes; (void)n_in; (void)out_size; (void)ws_size;

  char* ws      = (char*)d_ws;
  int*  lengths = (int*)ws;                 // 1 KB
  int*  flags   = (int*)(ws + 1024);        // 1 KB
  f16*  hbuf    = (f16*)(ws + 4096);        // 2 * 256 * 512 * 2B = 512 KB

  prep_kernel<<<dim3(Bn), dim3(256), 0, stream>>>(seq, lengths, flags, hbuf);

  void* args[] = { (void*)&seq, (void*)&emb, (void*)&Wi, (void*)&Wh, (void*)&bl,
                   (void*)&lengths, (void*)&flags, (void*)&hbuf };
  (void)hipLaunchCooperativeKernel((void*)lstm_kernel, dim3(256), dim3(256), args, 0, stream);

  ff_kernel<<<dim3(Bn), dim3(256), 0, stream>>>(hbuf, W1, b1, W2, b2, (float*)d_out);
}

// Round 5
// 5960.927 us; speedup vs baseline: 1.8089x; 1.8089x over previous
//
#include <hip/hip_runtime.h>
#include <hip/hip_fp16.h>

// Problem constants
#define Bn  256
#define Tn  512
#define En  256
#define Hn  512
#define G4n 2048   // 4*H
#define KKn 768    // E + H
#define FHn 512

typedef _Float16 f16;
typedef _Float16 f16x8 __attribute__((ext_vector_type(8)));
typedef _Float16 f16x4 __attribute__((ext_vector_type(4)));
typedef float    f32x4 __attribute__((ext_vector_type(4)));
typedef unsigned long long ull;

#define LDK 776   // padded LDS row length (16B-aligned stride; b128 aliasing is 2-way = free)
#define CNT_STRIDE 32   // ints: one 128B cache line per group counter

__device__ __forceinline__ float frcp(float x) { return __builtin_amdgcn_rcpf(x); }
__device__ __forceinline__ float fsig(float x) { return frcp(1.f + __expf(-x)); }
__device__ __forceinline__ float ftanh(float x) {
  x = fminf(fmaxf(x, -15.f), 15.f);
  float e = __expf(2.f * x);
  return 1.f - 2.f * frcp(e + 1.f);
}

// ---------------------------------------------------------------------------
// prep: lengths[b], zero group counters, zero h-buffer[0]
// ---------------------------------------------------------------------------
__global__ void prep_kernel(const int* __restrict__ seq, int* __restrict__ lengths,
                            int* __restrict__ cnt, f16* __restrict__ hbuf) {
  const int b = blockIdx.x, tid = threadIdx.x;
  __shared__ int red[256];
  int c = 0;
  for (int t = tid; t < Tn; t += 256) c += (seq[b * Tn + t] != 0) ? 1 : 0;
  red[tid] = c;
  __syncthreads();
  for (int s = 128; s > 0; s >>= 1) { if (tid < s) red[tid] += red[tid + s]; __syncthreads(); }
  if (tid == 0) lengths[b] = red[0];
  if (b == 0 && tid < 8) cnt[tid * CNT_STRIDE] = 0;
  f16* row = hbuf + (size_t)b * Hn;   // hbuf[0][b][:]
  for (int k = tid; k < Hn; k += 256) row[k] = (f16)0.f;
}

// ---------------------------------------------------------------------------
// Persistent cooperative LSTM kernel.
// Grid = 256 blocks: ig = blockIdx>>6 (batch group of 64), jg = blockIdx&63
// (owns h-cols jg*8..jg*8+8 -> gate cols {g*512 + jg*8 + 0..8}).
// LDS: act[64][768] f16 = [x_t ; h_t]; wt[32][768] f16 (row = g*8+h).
// h exchanged via double-buffered global f16 hbuf using device-coherent
// (agent-scope, sc0sc1) 8B atomic loads/stores -> NO L2 writeback/invalidate
// fences. Per-group step barrier = one monotonic counter (one cache line per
// group): fetch_add after the post-store __syncthreads (vmcnt(0) => h at the
// coherence point), poll until cnt >= 64*(t+1). Publish-before-poll =>
// deadlock-free; watchdog bounds every spin regardless.
// ---------------------------------------------------------------------------
__global__ __launch_bounds__(256)
void lstm_kernel(const int* __restrict__ seq, const float* __restrict__ emb,
                 const float* __restrict__ Wi, const float* __restrict__ Wh,
                 const float* __restrict__ bl,
                 const int* __restrict__ lengths, int* __restrict__ cnt,
                 f16* __restrict__ hbuf)
{
  __shared__ f16 act[64][LDK];
  __shared__ f16 wt[32][LDK];
  __shared__ __align__(16) f16 hstage[64][8];

  const int tid   = threadIdx.x;
  const int bx    = blockIdx.x;
  const int ig    = bx >> 6;
  const int jg    = bx & 63;
  const int bbase = ig * 64;
  const int lane  = tid & 63;
  const int wv    = tid >> 6;          // wave 0..3, handles batch rows wv*16..+16

  // ---- stage weight slice once: wt[g*8+h][k], k<256 from Wi, else Wh ----
  {
    const int h = tid & 7, g = (tid >> 3) & 3, k0 = tid >> 5;  // k0 in 0..7
    const int gc = g * Hn + jg * 8 + h;
    for (int k = k0; k < KKn; k += 8) {
      float w = (k < En) ? Wi[(size_t)k * G4n + gc] : Wh[(size_t)(k - En) * G4n + gc];
      wt[g * 8 + h][k] = (f16)w;
    }
  }

  const int ca    = lane & 15;      // MFMA M/N index
  const int hcol  = ca & 7;
  const int gA    = ca >> 3;        // 0 -> gate i (or g), 1 -> gate f (or o)
  const float biasA = bl[gA * Hn + jg * 8 + hcol];         // i/f bias
  const float biasB = bl[(2 + gA) * Hn + jg * 8 + hcol];   // g/o bias

  int   lens[4];
  float hreg[4] = {0.f, 0.f, 0.f, 0.f};
  float creg[4] = {0.f, 0.f, 0.f, 0.f};
  const int lrow0 = wv * 16 + ((lane >> 4) & 3) * 4;       // local row of j=0
#pragma unroll
  for (int j = 0; j < 4; ++j) lens[j] = lengths[bbase + lrow0 + j];
  const bool active = (lane & 8) == 0;  // lanes that own (batch, hcol) state

  // ---- initial staging: x(t=0) and h(0)=0 from hbuf[0] (plain loads ok:
  //      kernel-boundary coherence covers prep's writes) ----
  for (int r = wv; r < 64; r += 4) {
    int tok = seq[(size_t)(bbase + r) * Tn + 0];
    const float4 v = *(const float4*)(emb + (size_t)tok * En + lane * 4);
    f16x4 o = { (f16)v.x, (f16)v.y, (f16)v.z, (f16)v.w };
    *(f16x4*)&act[r][lane * 4] = o;
  }
  for (int r = wv; r < 64; r += 4) {
    f16x8 hv = *(const f16x8*)(hbuf + (size_t)(bbase + r) * Hn + lane * 8);
    *(f16x8*)&act[r][En + lane * 8] = hv;
  }
  __syncthreads();

  const int arow = wv * 16 + ca;        // MFMA A row (batch within group)
  const int koff = (lane >> 4) * 8;     // per-lane k offset within 32-k tile
  int cur = 0;

  for (int t = 0; t < Tn; ++t) {
    f32x4 acc0 = {0.f, 0.f, 0.f, 0.f};  // gate cols 0..15  (i | f)
    f32x4 acc1 = {0.f, 0.f, 0.f, 0.f};  // gate cols 16..31 (g | o)
#pragma unroll
    for (int kt = 0; kt < KKn; kt += 32) {
      f16x8 a  = *(const f16x8*)&act[arow][kt + koff];
      f16x8 b0 = *(const f16x8*)&wt[ca][kt + koff];
      f16x8 b1 = *(const f16x8*)&wt[16 + ca][kt + koff];
      acc0 = __builtin_amdgcn_mfma_f32_16x16x32_f16(a, b0, acc0, 0, 0, 0);
      acc1 = __builtin_amdgcn_mfma_f32_16x16x32_f16(a, b1, acc1, 0, 0, 0);
    }
#pragma unroll
    for (int j = 0; j < 4; ++j) { acc0[j] += biasA; acc1[j] += biasB; }

    // exchange with partner lane (^8): partner holds f / o for the same hcol
    float p0[4], p1[4];
#pragma unroll
    for (int j = 0; j < 4; ++j) {
      p0[j] = __shfl_xor(acc0[j], 8, 64);
      p1[j] = __shfl_xor(acc1[j], 8, 64);
    }

    if (active) {
#pragma unroll
      for (int j = 0; j < 4; ++j) {
        float iv = fsig(acc0[j]);
        float fv = fsig(p0[j]);
        float gv = ftanh(acc1[j]);
        float ov = fsig(p1[j]);
        float cn = fv * creg[j] + iv * gv;
        float hn = ov * ftanh(cn);
        if (t < lens[j]) { creg[j] = cn; hreg[j] = hn; }
        hstage[lrow0 + j][hcol] = (f16)hreg[j];   // always publish current h
      }
    }
    __syncthreads();                                  // (A) hstage visible

    const int nxt = cur ^ 1;
    // cooperative coherent h store: 64 rows x 16B = 128 chunks of 8B
    if (tid < 128) {
      const int row = tid >> 1, half = tid & 1;
      ull v = ((const ull*)&hstage[row][0])[half];
      ull* dst = (ull*)(hbuf + (size_t)nxt * Bn * Hn + (size_t)(bbase + row) * Hn + jg * 8);
      __hip_atomic_store(&dst[half], v, __ATOMIC_RELAXED, __HIP_MEMORY_SCOPE_AGENT);
    }
    __syncthreads();                                  // (B) vmcnt(0): h at coherence point
    if (t == Tn - 1) break;

    if (tid == 0)
      __hip_atomic_fetch_add(&cnt[ig * CNT_STRIDE], 1, __ATOMIC_RELAXED, __HIP_MEMORY_SCOPE_AGENT);

    // stage x for t+1 (overlaps other blocks' progress)
    for (int r = wv; r < 64; r += 4) {
      int tok = seq[(size_t)(bbase + r) * Tn + (t + 1)];
      const float4 v = *(const float4*)(emb + (size_t)tok * En + lane * 4);
      f16x4 o = { (f16)v.x, (f16)v.y, (f16)v.z, (f16)v.w };
      *(f16x4*)&act[r][lane * 4] = o;
    }

    // wait for all 64 blocks of this group to finish step t
    if (wv == 0) {
      const int target = 64 * (t + 1);
      int guard = 0;
      while (__hip_atomic_load(&cnt[ig * CNT_STRIDE], __ATOMIC_RELAXED, __HIP_MEMORY_SCOPE_AGENT) < target) {
        if (++guard > (1 << 13)) break;      // degrade, never wedge
        __builtin_amdgcn_s_sleep(2);
      }
    }
    __syncthreads();                                  // (C)

    // stage h(t+1) via device-coherent loads (bypass stale L1/L2)
    {
      const f16* hb = hbuf + (size_t)nxt * Bn * Hn;
      for (int r = wv; r < 64; r += 4) {
        const ull* src = (const ull*)(hb + (size_t)(bbase + r) * Hn);
        ull a = __hip_atomic_load(&src[lane * 2 + 0], __ATOMIC_RELAXED, __HIP_MEMORY_SCOPE_AGENT);
        ull b = __hip_atomic_load(&src[lane * 2 + 1], __ATOMIC_RELAXED, __HIP_MEMORY_SCOPE_AGENT);
        union { ull u[2]; f16x8 v; } tmp;
        tmp.u[0] = a; tmp.u[1] = b;
        *(f16x8*)&act[r][En + lane * 8] = tmp.v;
      }
    }
    __syncthreads();                                  // (D)
    cur = nxt;
  }
}

// ---------------------------------------------------------------------------
// FF head: hidden = tanh(h @ W1 + b1); logits = hidden @ W2 + b2; softmax.
// One block per batch. Final h lives in hbuf[0] (written at t=511).
// ---------------------------------------------------------------------------
__global__ void ff_kernel(const f16* __restrict__ hbuf0, const float* __restrict__ W1,
                          const float* __restrict__ b1, const float* __restrict__ W2,
                          const float* __restrict__ b2, float* __restrict__ out) {
  const int b = blockIdx.x, tid = threadIdx.x;
  __shared__ float hl[Hn];
  __shared__ float hid[FHn];
  __shared__ float red0[256], red1[256];
  for (int k = tid; k < Hn; k += 256) hl[k] = (float)hbuf0[(size_t)b * Hn + k];
  __syncthreads();
  for (int j = tid; j < FHn; j += 256) {
    float s = b1[j];
    for (int k = 0; k < Hn; ++k) s += hl[k] * W1[(size_t)k * FHn + j];
    hid[j] = ftanh(s);
  }
  __syncthreads();
  float p0 = 0.f, p1 = 0.f;
  for (int j = tid; j < FHn; j += 256) {
    p0 += hid[j] * W2[j * 2 + 0];
    p1 += hid[j] * W2[j * 2 + 1];
  }
  red0[tid] = p0; red1[tid] = p1;
  __syncthreads();
  for (int s = 128; s > 0; s >>= 1) {
    if (tid < s) { red0[tid] += red0[tid + s]; red1[tid] += red1[tid + s]; }
    __syncthreads();
  }
  if (tid == 0) {
    float l0 = red0[0] + b2[0], l1 = red1[0] + b2[1];
    float m = fmaxf(l0, l1);
    float e0 = __expf(l0 - m), e1 = __expf(l1 - m);
    float inv = frcp(e0 + e1);
    out[b * 2 + 0] = e0 * inv;
    out[b * 2 + 1] = e1 * inv;
  }
}

// ---------------------------------------------------------------------------
extern "C" void kernel_launch(void* const* d_in, const int* in_sizes, int n_in,
                              void* d_out, int out_size, void* d_ws, size_t ws_size,
                              hipStream_t stream) {
  const int*   seq = (const int*)d_in[0];
  const float* emb = (const float*)d_in[1];
  const float* Wi  = (const float*)d_in[2];
  const float* Wh  = (const float*)d_in[3];
  const float* bl  = (const float*)d_in[4];
  const float* W1  = (const float*)d_in[5];
  const float* b1  = (const float*)d_in[6];
  const float* W2  = (const float*)d_in[7];
  const float* b2  = (const float*)d_in[8];
  (void)in_sizes; (void)n_in; (void)out_size; (void)ws_size;

  char* ws      = (char*)d_ws;
  int*  lengths = (int*)ws;                 // 1 KB
  int*  cnt     = (int*)(ws + 1024);        // 8 counters, 128B apart
  f16*  hbuf    = (f16*)(ws + 8192);        // 2 * 256 * 512 * 2B = 512 KB

  prep_kernel<<<dim3(Bn), dim3(256), 0, stream>>>(seq, lengths, cnt, hbuf);

  void* args[] = { (void*)&seq, (void*)&emb, (void*)&Wi, (void*)&Wh, (void*)&bl,
                   (void*)&lengths, (void*)&cnt, (void*)&hbuf };
  (void)hipLaunchCooperativeKernel((void*)lstm_kernel, dim3(256), dim3(256), args, 0, stream);

  ff_kernel<<<dim3(Bn), dim3(256), 0, stream>>>(hbuf, W1, b1, W2, b2, (float*)d_out);
}

// Round 6
// 3220.860 us; speedup vs baseline: 3.3478x; 1.8507x over previous
//
#include <hip/hip_runtime.h>
#include <hip/hip_fp16.h>

// Problem constants
#define Bn  256
#define Tn  512
#define En  256
#define Hn  512
#define G4n 2048   // 4*H
#define KKn 768    // E + H
#define FHn 512

#define GB  32     // batch rows per XCD group
#define NB  32     // blocks per XCD group
#define NH  16     // h-cols per block (x4 gates = 64 gate cols)
#define LDK 776    // padded LDS row (f16), 16B-aligned stride
#define CSTRIDE 64 // ints between per-XCD counters (256B)

typedef _Float16 f16;
typedef _Float16 f16x8 __attribute__((ext_vector_type(8)));
typedef _Float16 f16x4 __attribute__((ext_vector_type(4)));
typedef float    f32x4 __attribute__((ext_vector_type(4)));

__device__ __forceinline__ float frcp(float x) { return __builtin_amdgcn_rcpf(x); }
__device__ __forceinline__ float fsig(float x) { return frcp(1.f + __expf(-x)); }
__device__ __forceinline__ float ftanh(float x) {
  x = fminf(fmaxf(x, -15.f), 15.f);
  float e = __expf(2.f * x);
  return 1.f - 2.f * frcp(e + 1.f);
}

// ---- XCD-local primitives (L2 scope; no sc1 => never touches the MALL) ----
__device__ __forceinline__ int read_xcc_id() {
  int x;
  asm volatile("s_getreg_b32 %0, hwreg(HW_REG_XCC_ID)" : "=s"(x));
  return x & 7;
}
__device__ __forceinline__ void store_x4_sc0(f16* p, f16x8 v) {
  asm volatile("global_store_dwordx4 %0, %1, off sc0" :: "v"(p), "v"(v) : "memory");
}
__device__ __forceinline__ f16x8 load_x4_sc0(const f16* p) {   // no waitcnt!
  f16x8 r;
  asm volatile("global_load_dwordx4 %0, %1, off sc0" : "=v"(r) : "v"(p) : "memory");
  return r;
}
__device__ __forceinline__ void waitcnt_vm0() {
  asm volatile("s_waitcnt vmcnt(0)" ::: "memory");
}
__device__ __forceinline__ void atomic_inc_l2(int* p) {
  int one = 1;
  asm volatile("global_atomic_add %0, %1, off" :: "v"(p), "v"(one) : "memory");
}
__device__ __forceinline__ int load_i32_sc0(const int* p) {
  int r;
  asm volatile("global_load_dword %0, %1, off sc0\n\ts_waitcnt vmcnt(0)"
               : "=v"(r) : "v"(p) : "memory");
  return r;
}

// ---------------------------------------------------------------------------
// prep: lengths[b], zero slot/barrier counters, zero h-buffer[0]
// ---------------------------------------------------------------------------
__global__ void prep_kernel(const int* __restrict__ seq, int* __restrict__ lengths,
                            int* __restrict__ slotc, int* __restrict__ cnt,
                            f16* __restrict__ hbuf) {
  const int b = blockIdx.x, tid = threadIdx.x;
  __shared__ int red[256];
  int c = 0;
  for (int t = tid; t < Tn; t += 256) c += (seq[b * Tn + t] != 0) ? 1 : 0;
  red[tid] = c;
  __syncthreads();
  for (int s = 128; s > 0; s >>= 1) { if (tid < s) red[tid] += red[tid + s]; __syncthreads(); }
  if (tid == 0) lengths[b] = red[0];
  if (b == 0 && tid < 8) { slotc[tid * CSTRIDE] = 0; cnt[tid * CSTRIDE] = 0; }
  f16* row = hbuf + (size_t)b * Hn;   // hbuf[0][b][:]
  for (int k = tid; k < Hn; k += 256) row[k] = (f16)0.f;
}

// ---------------------------------------------------------------------------
// Persistent cooperative LSTM. 256 blocks, 150KB LDS => exactly 1 block/CU =>
// exactly 32 blocks per XCD. group = physical XCD (read via HW_REG_XCC_ID),
// slot = XCD-local atomic ticket (0..31). Block handles batches xcd*32..+32,
// h-cols slot*16..+16 (gate cols gate*512 + slot*16 + 0..15).
// All cross-block state (h tiles, barrier counter) is exclusive to one XCD =>
// L2-coherent with sc0 (L1-bypass) ops; no MALL traffic in the loop.
// Wave w owns one 16-col n-tile: cols = gate(ca>>2) x hloc(ca&3), covering
// h-cols slot*16 + w*4 + (0..3). Owners (ca&12)==0 hold c/h for 2x4 rows.
// ---------------------------------------------------------------------------
__global__ __launch_bounds__(256)
void lstm_kernel(const int* __restrict__ seq, const float* __restrict__ emb,
                 const float* __restrict__ Wi, const float* __restrict__ Wh,
                 const float* __restrict__ bl,
                 const int* __restrict__ lengths, int* __restrict__ slotc,
                 int* __restrict__ cnt, f16* __restrict__ hbuf)
{
  __shared__ f16 act[GB][LDK];                 // [x_t ; h_t] for 32 batches
  __shared__ f16 wt[64][LDK];                  // 64 gate cols
  __shared__ __align__(16) f16 hstage[GB][NH];
  __shared__ int s_ids[2];

  const int tid  = threadIdx.x;
  const int lane = tid & 63;
  const int wv   = tid >> 6;

  if (tid == 0) {
    int x = read_xcc_id();
    s_ids[0] = x;
    s_ids[1] = __hip_atomic_fetch_add(&slotc[x * CSTRIDE], 1,
                                      __ATOMIC_RELAXED, __HIP_MEMORY_SCOPE_WORKGROUP) & 31;
  }
  __syncthreads();
  const int xcd   = s_ids[0];
  const int slot  = s_ids[1];
  const int bbase = xcd * GB;
  int* const bar  = cnt + xcd * CSTRIDE;

  // ---- stage weights: wt[c][k], c = w*16 + gate*4 + hloc ----
  {
    const int c = tid & 63, k0 = tid >> 6;
    const int gate = (c >> 2) & 3, w = c >> 4, hl = c & 3;
    const int gc = gate * Hn + slot * NH + w * 4 + hl;
    for (int k = k0; k < KKn; k += 4) {
      float wval = (k < En) ? Wi[(size_t)k * G4n + gc] : Wh[(size_t)(k - En) * G4n + gc];
      wt[c][k] = (f16)wval;
    }
  }

  const int ca   = lane & 15;          // col within wave's n-tile
  const int gate = ca >> 2, hloc = ca & 3;
  const float bias = bl[gate * Hn + slot * NH + wv * 4 + hloc];
  const int r0 = (lane >> 4) * 4;      // C/D row base (j=0)
  const bool owner = (ca & 12) == 0;   // lanes owning (row, hcol) state

  int   lens[2][4];
  float hreg[2][4] = {{0,0,0,0},{0,0,0,0}};
  float creg[2][4] = {{0,0,0,0},{0,0,0,0}};
#pragma unroll
  for (int mt = 0; mt < 2; ++mt)
#pragma unroll
    for (int j = 0; j < 4; ++j)
      lens[mt][j] = lengths[bbase + mt * 16 + r0 + j];

  // ---- initial staging: x(0) and h(0)=0 (plain loads; dispatch-boundary coherent)
  for (int r = wv; r < GB; r += 4) {
    int tok = seq[(size_t)(bbase + r) * Tn + 0];
    const float4 v = *(const float4*)(emb + (size_t)tok * En + lane * 4);
    f16x4 o = { (f16)v.x, (f16)v.y, (f16)v.z, (f16)v.w };
    *(f16x4*)&act[r][lane * 4] = o;
  }
  for (int r = wv; r < GB; r += 4)
    *(f16x8*)&act[r][En + lane * 8] = *(const f16x8*)(hbuf + (size_t)(bbase + r) * Hn + lane * 8);
  __syncthreads();

  const int koff = (lane >> 4) * 8;
  int cur = 0;

  for (int t = 0; t < Tn; ++t) {
    f32x4 acc[2] = {{0,0,0,0},{0,0,0,0}};
#pragma unroll
    for (int kt = 0; kt < KKn; kt += 32) {
      f16x8 b = *(const f16x8*)&wt[wv * 16 + ca][kt + koff];
#pragma unroll
      for (int mt = 0; mt < 2; ++mt) {
        f16x8 a = *(const f16x8*)&act[mt * 16 + ca][kt + koff];
        acc[mt] = __builtin_amdgcn_mfma_f32_16x16x32_f16(a, b, acc[mt], 0, 0, 0);
      }
    }
#pragma unroll
    for (int mt = 0; mt < 2; ++mt)
#pragma unroll
      for (int j = 0; j < 4; ++j) acc[mt][j] += bias;

    // gather f/g/o onto i-lanes (cols: i=0..3, f=4..7, g=8..11, o=12..15)
#pragma unroll
    for (int mt = 0; mt < 2; ++mt) {
      float fv[4], gv[4], ov[4];
#pragma unroll
      for (int j = 0; j < 4; ++j) {
        fv[j] = __shfl_xor(acc[mt][j], 4, 64);
        gv[j] = __shfl_xor(acc[mt][j], 8, 64);
        ov[j] = __shfl_xor(acc[mt][j], 12, 64);
      }
      if (owner) {
#pragma unroll
        for (int j = 0; j < 4; ++j) {
          float iv = fsig(acc[mt][j]);
          float ff = fsig(fv[j]);
          float gg = ftanh(gv[j]);
          float oo = fsig(ov[j]);
          float cn = ff * creg[mt][j] + iv * gg;
          float hn = oo * ftanh(cn);
          if (t < lens[mt][j]) { creg[mt][j] = cn; hreg[mt][j] = hn; }
          hstage[mt * 16 + r0 + j][wv * 4 + ca] = (f16)hreg[mt][j];
        }
      }
    }
    __syncthreads();                                  // (A) hstage complete

    const int nxt = cur ^ 1;
    if (tid < 64) {                                   // 32 rows x 32B -> L2 (sc0)
      const int row = tid >> 1, half = tid & 1;
      f16x8 v = ((const f16x8*)&hstage[row][0])[half];
      f16* dst = hbuf + ((size_t)nxt * Bn + (bbase + row)) * Hn + slot * NH + half * 8;
      store_x4_sc0(dst, v);
    }
    waitcnt_vm0();
    __syncthreads();                                  // (B) h tile in L2
    if (t == Tn - 1) break;

    if (tid == 0) atomic_inc_l2(bar);                 // publish step t (L2 atomic)

    // stage x(t+1) while others catch up
    for (int r = wv; r < GB; r += 4) {
      int tok = seq[(size_t)(bbase + r) * Tn + (t + 1)];
      const float4 v = *(const float4*)(emb + (size_t)tok * En + lane * 4);
      f16x4 o = { (f16)v.x, (f16)v.y, (f16)v.z, (f16)v.w };
      *(f16x4*)&act[r][lane * 4] = o;
    }

    // wait for all 32 blocks of this XCD
    if (wv == 0) {
      const int target = NB * (t + 1);
      int guard = 0;
      while (load_i32_sc0(bar) < target) {
        if (++guard > (1 << 13)) break;               // degrade, never wedge
        __builtin_amdgcn_s_sleep(1);
      }
    }
    __syncthreads();                                  // (C)

    // load h(t+1): 8 rows/wave, 16B/lane, sc0 (L1-bypass, L2-hit)
    {
      const f16* hb = hbuf + (size_t)nxt * Bn * Hn;
      f16x8 hv[8];
#pragma unroll
      for (int i = 0; i < 8; ++i)
        hv[i] = load_x4_sc0(hb + (size_t)(bbase + wv + i * 4) * Hn + lane * 8);
      waitcnt_vm0();
#pragma unroll
      for (int i = 0; i < 8; ++i)
        *(f16x8*)&act[wv + i * 4][En + lane * 8] = hv[i];
    }
    __syncthreads();                                  // (D)
    cur = nxt;
  }
}

// ---------------------------------------------------------------------------
// FF head: hidden = tanh(h @ W1 + b1); logits = hidden @ W2 + b2; softmax.
// Final h lives in hbuf[0] (t=511 writes buffer 512%2 == 0).
// ---------------------------------------------------------------------------
__global__ void ff_kernel(const f16* __restrict__ hbuf0, const float* __restrict__ W1,
                          const float* __restrict__ b1, const float* __restrict__ W2,
                          const float* __restrict__ b2, float* __restrict__ out) {
  const int b = blockIdx.x, tid = threadIdx.x;
  __shared__ float hl[Hn];
  __shared__ float hid[FHn];
  __shared__ float red0[256], red1[256];
  for (int k = tid; k < Hn; k += 256) hl[k] = (float)hbuf0[(size_t)b * Hn + k];
  __syncthreads();
  for (int j = tid; j < FHn; j += 256) {
    float s = b1[j];
    for (int k = 0; k < Hn; ++k) s += hl[k] * W1[(size_t)k * FHn + j];
    hid[j] = ftanh(s);
  }
  __syncthreads();
  float p0 = 0.f, p1 = 0.f;
  for (int j = tid; j < FHn; j += 256) {
    p0 += hid[j] * W2[j * 2 + 0];
    p1 += hid[j] * W2[j * 2 + 1];
  }
  red0[tid] = p0; red1[tid] = p1;
  __syncthreads();
  for (int s = 128; s > 0; s >>= 1) {
    if (tid < s) { red0[tid] += red0[tid + s]; red1[tid] += red1[tid + s]; }
    __syncthreads();
  }
  if (tid == 0) {
    float l0 = red0[0] + b2[0], l1 = red1[0] + b2[1];
    float m = fmaxf(l0, l1);
    float e0 = __expf(l0 - m), e1 = __expf(l1 - m);
    float inv = frcp(e0 + e1);
    out[b * 2 + 0] = e0 * inv;
    out[b * 2 + 1] = e1 * inv;
  }
}

// ---------------------------------------------------------------------------
extern "C" void kernel_launch(void* const* d_in, const int* in_sizes, int n_in,
                              void* d_out, int out_size, void* d_ws, size_t ws_size,
                              hipStream_t stream) {
  const int*   seq = (const int*)d_in[0];
  const float* emb = (const float*)d_in[1];
  const float* Wi  = (const float*)d_in[2];
  const float* Wh  = (const float*)d_in[3];
  const float* bl  = (const float*)d_in[4];
  const float* W1  = (const float*)d_in[5];
  const float* b1  = (const float*)d_in[6];
  const float* W2  = (const float*)d_in[7];
  const float* b2  = (const float*)d_in[8];
  (void)in_sizes; (void)n_in; (void)out_size; (void)ws_size;

  char* ws      = (char*)d_ws;
  int*  lengths = (int*)ws;                 // 1 KB
  int*  slotc   = (int*)(ws + 1024);        // 8 counters, 256B apart
  int*  cnt     = (int*)(ws + 4096);        // 8 counters, 256B apart
  f16*  hbuf    = (f16*)(ws + 8192);        // 2 * 256 * 512 * 2B = 512 KB

  prep_kernel<<<dim3(Bn), dim3(256), 0, stream>>>(seq, lengths, slotc, cnt, hbuf);

  void* args[] = { (void*)&seq, (void*)&emb, (void*)&Wi, (void*)&Wh, (void*)&bl,
                   (void*)&lengths, (void*)&slotc, (void*)&cnt, (void*)&hbuf };
  (void)hipLaunchCooperativeKernel((void*)lstm_kernel, dim3(256), dim3(256), args, 0, stream);

  ff_kernel<<<dim3(Bn), dim3(256), 0, stream>>>(hbuf, W1, b1, W2, b2, (float*)d_out);
}